// Round 1
// baseline (1020.475 us; speedup 1.0000x reference)
//
#include <hip/hip_runtime.h>

#define NODES 100000

// ---------------- CSR build ----------------

__global__ __launch_bounds__(256) void zero_k(int* __restrict__ p, int n) {
  int i = blockIdx.x * 256 + threadIdx.x;
  if (i < n) p[i] = 0;
}

__global__ __launch_bounds__(256) void hist_k(const int* __restrict__ col, int* __restrict__ cnt, int E) {
  int i = blockIdx.x * 256 + threadIdx.x;
  if (i < E) atomicAdd(&cnt[col[i]], 1);
}

__global__ __launch_bounds__(256) void dis_k(const int* __restrict__ cnt, float* __restrict__ dis, int n) {
  int i = blockIdx.x * 256 + threadIdx.x;
  if (i < n) dis[i] = rsqrtf((float)(cnt[i] + 1));  // +1 self loop; deg >= 1 always
}

// exclusive scan, 1024 elements/block (256 threads x 4)
__global__ __launch_bounds__(256) void scan1_k(const int* __restrict__ in, int* __restrict__ out,
                                               int* __restrict__ bsums, int n) {
  __shared__ int lds[256];
  int t = threadIdx.x;
  int base = blockIdx.x * 1024 + t * 4;
  int v0 = 0, v1 = 0, v2 = 0, v3 = 0;
  if (base + 0 < n) v0 = in[base + 0];
  if (base + 1 < n) v1 = in[base + 1];
  if (base + 2 < n) v2 = in[base + 2];
  if (base + 3 < n) v3 = in[base + 3];
  int s = v0 + v1 + v2 + v3;
  lds[t] = s;
  __syncthreads();
  for (int off = 1; off < 256; off <<= 1) {
    int y = (t >= off) ? lds[t - off] : 0;
    __syncthreads();
    lds[t] += y;
    __syncthreads();
  }
  int excl = lds[t] - s;  // exclusive prefix of this thread's 4
  if (t == 255) bsums[blockIdx.x] = lds[255];
  if (base + 0 < n) out[base + 0] = excl; excl += v0;
  if (base + 1 < n) out[base + 1] = excl; excl += v1;
  if (base + 2 < n) out[base + 2] = excl; excl += v2;
  if (base + 3 < n) out[base + 3] = excl;
}

__global__ __launch_bounds__(256) void scan2_k(int* __restrict__ bs, int nb) {
  __shared__ int lds[256];
  int t = threadIdx.x;
  int v = (t < nb) ? bs[t] : 0;
  lds[t] = v;
  __syncthreads();
  for (int off = 1; off < 256; off <<= 1) {
    int y = (t >= off) ? lds[t - off] : 0;
    __syncthreads();
    lds[t] += y;
    __syncthreads();
  }
  if (t < nb) bs[t] = lds[t] - v;  // exclusive, in place
}

__global__ __launch_bounds__(256) void scan3_k(int* __restrict__ offs, int* __restrict__ curs,
                                               const int* __restrict__ bs, int n, int E) {
  int b = blockIdx.x, t = threadIdx.x;
  int add = bs[b];
  int base = b * 1024 + t * 4;
#pragma unroll
  for (int j = 0; j < 4; ++j) {
    int i = base + j;
    if (i < n) {
      int val = offs[i] + add;
      offs[i] = val;
      curs[i] = val;
    }
  }
  if (b == 0 && t == 0) offs[n] = E;
}

__global__ __launch_bounds__(256) void fill_k(const int* __restrict__ row, const int* __restrict__ col,
                                              int* __restrict__ curs, int* __restrict__ adj, int E) {
  int i = blockIdx.x * 256 + threadIdx.x;
  if (i < E) {
    int p = atomicAdd(&curs[col[i]], 1);
    adj[p] = row[i];
  }
}

// ---------------- GEMM: G[node,:] = (X[node,:] @ W) * dis[node] ----------------
// 64 nodes/block, 256 threads: thread = (node_local = t>>2, chunk = t&3), CH outputs each.
// XS = LDS row stride for X tile (padded to dodge bank conflicts when K%32==0).
template <int K, int XS, int NOUT, int CH>
__global__ __launch_bounds__(256) void gemm_scale_k(const float* __restrict__ X,
                                                    const float* __restrict__ W,
                                                    const float* __restrict__ dis,
                                                    float* __restrict__ G, int n) {
  __shared__ float Xs[64 * XS];
  __shared__ float Ws[K * NOUT + 8];  // +8: 18-wide chunk layout over-reads by up to 2
  int t = threadIdx.x;
  int b0 = blockIdx.x * 64;
  for (int i = t; i < K * NOUT; i += 256) Ws[i] = W[i];
  int lim = n * K;
  for (int i = t; i < 64 * K; i += 256) {
    int r = i / K, c = i - r * K;
    int gi = b0 * K + i;
    Xs[r * XS + c] = (gi < lim) ? X[gi] : 0.f;
  }
  __syncthreads();
  int nl = t >> 2, ch = t & 3;
  float acc[CH];
#pragma unroll
  for (int j = 0; j < CH; ++j) acc[j] = 0.f;
  const float* xr = &Xs[nl * XS];
  const float* wc = &Ws[ch * CH];
  for (int k = 0; k < K; ++k) {
    float a = xr[k];
#pragma unroll
    for (int j = 0; j < CH; ++j) acc[j] = fmaf(a, wc[k * NOUT + j], acc[j]);
  }
  __syncthreads();  // done reading Xs; reuse as store-staging
  int node = b0 + nl;
  float s = (node < n) ? dis[node] : 0.f;
  constexpr int ST = NOUT + 1;  // padded staging stride (64*ST <= 64*XS holds for all instantiations)
#pragma unroll
  for (int j = 0; j < CH; ++j) {
    int jj = ch * CH + j;
    if (jj < NOUT) Xs[nl * ST + jj] = acc[j] * s;
  }
  __syncthreads();
  int gbase = b0 * NOUT;
  int glim = n * NOUT;
  for (int i = t; i < 64 * NOUT; i += 256) {
    int r = i / NOUT, c = i - r * NOUT;
    if (gbase + i < glim) G[gbase + i] = Xs[r * ST + c];
  }
}

// ---------------- Aggregation: out[c,:] = act(dis[c]*(sum_{r in N(c)} g[r,:] + g[c,:]) + b) ----------------
// one wave per node, lane = feature
template <int NOUT>
__global__ __launch_bounds__(256) void agg_k(const float* __restrict__ g,
                                             const int* __restrict__ offs,
                                             const int* __restrict__ adj,
                                             const float* __restrict__ dis,
                                             const float* __restrict__ bias,
                                             float* __restrict__ out, int n, int do_relu) {
  int node = blockIdx.x * 4 + (threadIdx.x >> 6);
  int lane = threadIdx.x & 63;
  if (node >= n) return;
  if (NOUT < 64 && lane >= NOUT) return;
  float acc = g[node * NOUT + lane];  // self loop (g already scaled by dis[node])
  int s = offs[node], e = offs[node + 1];
  int i = s;
  for (; i + 4 <= e; i += 4) {
    int r0 = adj[i], r1 = adj[i + 1], r2 = adj[i + 2], r3 = adj[i + 3];
    float a0 = g[r0 * NOUT + lane];
    float a1 = g[r1 * NOUT + lane];
    float a2 = g[r2 * NOUT + lane];
    float a3 = g[r3 * NOUT + lane];
    acc += a0 + a1 + a2 + a3;
  }
  for (; i < e; ++i) acc += g[adj[i] * NOUT + lane];
  float v = fmaf(dis[node], acc, bias[lane]);
  out[node * NOUT + lane] = do_relu ? fmaxf(v, 0.f) : v;
}

// ---------------- launch ----------------

extern "C" void kernel_launch(void* const* d_in, const int* in_sizes, int n_in,
                              void* d_out, int out_size, void* d_ws, size_t ws_size,
                              hipStream_t stream) {
  const float* x  = (const float*)d_in[0];
  const int*   ei = (const int*)d_in[1];
  const float* W1 = (const float*)d_in[2];
  const float* b1 = (const float*)d_in[3];
  const float* W2 = (const float*)d_in[4];
  const float* b2 = (const float*)d_in[5];
  const float* W3 = (const float*)d_in[6];
  const float* b3 = (const float*)d_in[7];
  const float* Wo = (const float*)d_in[8];
  const float* bo = (const float*)d_in[9];
  float* out = (float*)d_out;

  const int N = NODES;
  const int E = in_sizes[1] / 2;
  const int* rowp = ei;
  const int* colp = ei + E;

  char* p = (char*)d_ws;
  auto alloc = [&](size_t bytes) {
    void* r = (void*)p;
    p += (bytes + 255) & ~(size_t)255;
    return r;
  };
  int*   cnt  = (int*)alloc((size_t)N * 4);
  int*   curs = (int*)alloc((size_t)N * 4);
  int*   offs = (int*)alloc((size_t)(N + 1) * 4);
  float* dis  = (float*)alloc((size_t)N * 4);
  int*   bsum = (int*)alloc(256 * 4);
  int*   adj  = (int*)alloc((size_t)E * 4);
  float* bufA = (float*)alloc((size_t)N * 64 * 4);
  float* bufB = (float*)alloc((size_t)N * 64 * 4);

  int gN = (N + 255) / 256;
  int gE = (E + 255) / 256;
  int nb = (N + 1023) / 1024;  // 98 <= 256

  zero_k<<<gN, 256, 0, stream>>>(cnt, N);
  hist_k<<<gE, 256, 0, stream>>>(colp, cnt, E);
  dis_k<<<gN, 256, 0, stream>>>(cnt, dis, N);
  scan1_k<<<nb, 256, 0, stream>>>(cnt, offs, bsum, N);
  scan2_k<<<1, 256, 0, stream>>>(bsum, nb);
  scan3_k<<<nb, 256, 0, stream>>>(offs, curs, bsum, N, E);
  fill_k<<<gE, 256, 0, stream>>>(rowp, colp, curs, adj, E);

  int gG = (N + 63) / 64;
  int gA = (N + 3) / 4;

  gemm_scale_k<100, 100, 64, 16><<<gG, 256, 0, stream>>>(x, W1, dis, bufA, N);
  agg_k<64><<<gA, 256, 0, stream>>>(bufA, offs, adj, dis, b1, bufB, N, 1);

  gemm_scale_k<64, 65, 64, 16><<<gG, 256, 0, stream>>>(bufB, W2, dis, bufA, N);
  agg_k<64><<<gA, 256, 0, stream>>>(bufA, offs, adj, dis, b2, bufB, N, 1);

  gemm_scale_k<64, 65, 64, 16><<<gG, 256, 0, stream>>>(bufB, W3, dis, bufA, N);
  agg_k<64><<<gA, 256, 0, stream>>>(bufA, offs, adj, dis, b3, bufB, N, 1);

  gemm_scale_k<64, 65, 18, 5><<<gG, 256, 0, stream>>>(bufB, Wo, dis, bufA, N);
  agg_k<18><<<gA, 256, 0, stream>>>(bufA, offs, adj, dis, bo, out, N, 0);
}